// Round 14
// baseline (41.630 us; speedup 1.0000x reference)
//
#include <hip/hip_runtime.h>
#include <hip/hip_bf16.h>

// SkeletalConv via MFMA + LDS staging (fragment-contiguous layout) +
// LDS-transpose aligned-store epilogue + NONTEMPORAL full-line stores.
// x: (16, 25, 65536) f32, W: (48, 16, 16, 3) f32, b: (48, 16) f32
// out: (16, 24, 65534) f32
// out[co,e,t] = 0.5*sum_{j,ci,k} W[2e+j,co,ci,k]*x[ci,e+j,t+k] + 0.5*(b[2e,co]+b[2e+1,co])
//
// Staging layout lds[q][col][d], q=ci>>2, d=ci&3: one ds_read_b128 per
// (tile,tap) B-fragment. A = W-frag per lane from 6 aligned float4 loads.
// C row=co, col=t. Epilogue: C -> LDS [co][col] tile, then per-row
// 64B-line-aligned float4 stores.
// NEW: bulk stores are __builtin_nontemporal_store. Rationale: out's
// 101MB/iter write stream allocates in L2/LLC and evicts x (x+out = 206MB
// vs 256MB LLC; replay FETCH=60MB shows partial x residency). Writes are
// never re-read -> no-allocate keeps x LLC-resident. Safe now (unlike
// round 4's scalar-dword NT disaster): every NT store is a full 64B line
// (16-lane groups write 256B contiguous from a line-aligned base), so no
// partial-line RMW can occur. Boundary scalar stores remain cached.

#define NJ    25
#define LSEQ  65536
#define NE    24
#define LOUTN (LSEQ - 2)               // 65534 valid t
#define CQ    258                      // staging cols per quad (256 + 2 halo)
#define CWT   292                      // C-tile row stride (dwords), mult of 4
#define LDSN  (64 + 16 * CWT)          // 4736 dwords = 18944 B (>= staging 4128)

typedef __attribute__((ext_vector_type(8))) short bf16x8;
typedef __attribute__((ext_vector_type(4))) float f32x4;

static __device__ __forceinline__ unsigned cvtpk(float lo, float hi) {
    union { __hip_bfloat162 h; unsigned u; } cv;
    cv.h = __float22bfloat162_rn(make_float2(lo, hi));   // v_cvt_pk_bf16_f32
    return cv.u;
}

__global__ __launch_bounds__(256)
void skel_mfma_kernel(const float* __restrict__ x,
                      const float* __restrict__ W,
                      const float* __restrict__ b,
                      float* __restrict__ out)
{
    __shared__ unsigned lds[LDSN];      // staging tile, later aliased as C tile

    const int e   = blockIdx.y;
    const int tb  = blockIdx.x * 256;
    const int tid = threadIdx.x;
    const int l   = tid & 63, wv = tid >> 6;
    const int g   = l >> 4,  lc = l & 15;

    // ---- A fragments (W): lane l -> co=lc, slots kk=8g+i, 3 taps ----
    const float* wp = W + ((size_t)((2 * e) * 16 + lc) * 16 + 4 * g) * 3;
    f32x4 wj0[3], wj1[3];
    #pragma unroll
    for (int q = 0; q < 3; ++q) {
        wj0[q] = *reinterpret_cast<const f32x4*>(wp + 4 * q);
        wj1[q] = *reinterpret_cast<const f32x4*>(wp + 768 + 4 * q);
    }
    union { unsigned u[4]; bf16x8 v8; } Aw[3];
    #pragma unroll
    for (int d = 0; d < 4; ++d)
        #pragma unroll
        for (int k = 0; k < 3; ++k) {
            const int f = d * 3 + k;            // compile-time after unroll
            Aw[k].u[d] = cvtpk(wj0[f >> 2][f & 3], wj1[f >> 2][f & 3]);
        }

    // ---- folded bias for rows co = 4g+r ----
    const f32x4 b0 = *reinterpret_cast<const f32x4*>(b + (size_t)(2 * e) * 16 + 4 * g);
    const f32x4 b1 = *reinterpret_cast<const f32x4*>(b + (size_t)(2 * e + 1) * 16 + 4 * g);
    f32x4 bias;
    #pragma unroll
    for (int r = 0; r < 4; ++r) bias[r] = 0.5f * (b0[r] + b1[r]);

    // ---- stage: thread = (quad qs, col cs); 32 coalesced dword loads ----
    {
        const int qs = tid >> 6;                // quad (= wave)
        const int cs = tid & 63;
        const float* xr0 = x + (size_t)((4 * qs + 0) * NJ + e) * LSEQ + tb;
        const float* xr1 = x + (size_t)((4 * qs + 1) * NJ + e) * LSEQ + tb;
        const float* xr2 = x + (size_t)((4 * qs + 2) * NJ + e) * LSEQ + tb;
        const float* xr3 = x + (size_t)((4 * qs + 3) * NJ + e) * LSEQ + tb;
        #pragma unroll
        for (int s = 0; s < 4; ++s) {
            const int col = 64 * s + cs;        // never OOB (tb+255 <= 65535)
            uint4 pk;
            pk.x = cvtpk(xr0[col], xr0[col + LSEQ]);
            pk.y = cvtpk(xr1[col], xr1[col + LSEQ]);
            pk.z = cvtpk(xr2[col], xr2[col + LSEQ]);
            pk.w = cvtpk(xr3[col], xr3[col + LSEQ]);
            *reinterpret_cast<uint4*>(&lds[(qs * CQ + col) * 4]) = pk;
        }
    }
    if (tid < 32) {                             // halo cols 256,257 (all 16 ci)
        const int ci = tid >> 1, h = tid & 1;
        const int gc = min(tb + 256 + h, LSEQ - 1); // clamp (last chunk only)
        const float* xl = x + (size_t)(ci * NJ + e) * LSEQ;
        lds[((ci >> 2) * CQ + 256 + h) * 4 + (ci & 3)] = cvtpk(xl[gc], xl[gc + LSEQ]);
    }
    __syncthreads();

    // ---- compute: wave wv owns cols wv*64..wv*64+63; keep C in regs ----
    f32x4 C[4];
    #pragma unroll
    for (int tc = 0; tc < 4; ++tc) {
        const int cb = wv * 64 + tc * 16 + lc;      // col within chunk
        f32x4 acc = {0.f, 0.f, 0.f, 0.f};
        #pragma unroll
        for (int k = 0; k < 3; ++k) {
            union { uint4 q4; bf16x8 v8; } Bx;     // one b128 = whole fragment
            Bx.q4 = *reinterpret_cast<const uint4*>(&lds[(g * CQ + cb + k) * 4]);
            acc = __builtin_amdgcn_mfma_f32_16x16x32_bf16(Aw[k].v8, Bx.v8, acc, 0, 0, 0);
        }
        C[tc] = acc;
    }
    __syncthreads();                                // staging reads complete

    // ---- epilogue 1: final values -> LDS C-tile [co][col] ----
    {
        float* cl = reinterpret_cast<float*>(lds);
        int srw[4];
        #pragma unroll
        for (int r = 0; r < 4; ++r) {
            const int row = 4 * g + r;              // co
            const size_t rb = (size_t)(row * NE + e) * LOUTN + tb;
            srw[r] = (int)((16 - (rb & 15)) & 15);  // row alignment phase
        }
        #pragma unroll
        for (int tc = 0; tc < 4; ++tc) {
            const int cb = wv * 64 + tc * 16 + lc;
            #pragma unroll
            for (int r = 0; r < 4; ++r)
                cl[64 + (4 * g + r) * CWT + 16 + cb - srw[r]] = fmaf(0.5f, C[tc][r], bias[r]);
        }
    }
    __syncthreads();                                // C-tile complete

    // ---- epilogue 2: per-row 64B-line-aligned float4 stores (NT) ----
    {
        const float* cl = reinterpret_cast<const float*>(lds);
        const int row = tid >> 4;                   // co
        const int q   = tid & 15;
        const size_t rbase = (size_t)(row * NE + e) * LOUTN;
        const int srow = (int)((16 - ((rbase + tb) & 15)) & 15);
        #pragma unroll
        for (int s = 0; s < 5; ++s) {
            const int col = srow - 64 + 64 * s + 4 * q;   // block-frame col
            const f32x4 v = *reinterpret_cast<const f32x4*>(
                cl + 64 + row * CWT - 48 + 64 * s + 4 * q);
            const long t = (long)tb + col;
            if (col >= 0 && col + 3 < 256 && t + 3 < LOUTN) {
                // full 64B line per 4-lane group, line-aligned -> NT safe
                __builtin_nontemporal_store(v,
                    reinterpret_cast<f32x4*>(out + rbase + t));
            } else {
                #pragma unroll
                for (int d = 0; d < 4; ++d)
                    if (col + d >= 0 && col + d < 256 && t + d < LOUTN)
                        out[rbase + t + d] = v[d];
            }
        }
    }
}

extern "C" void kernel_launch(void* const* d_in, const int* in_sizes, int n_in,
                              void* d_out, int out_size, void* d_ws, size_t ws_size,
                              hipStream_t stream)
{
    const float* x = (const float*)d_in[0];
    const float* W = (const float*)d_in[1];
    const float* b = (const float*)d_in[2];
    float* out     = (float*)d_out;

    dim3 grid((LOUTN + 255) / 256, NE);      // 256 x 24 blocks, single launch
    skel_mfma_kernel<<<grid, 256, 0, stream>>>(x, W, b, out);
}

// Round 15
// 41.029 us; speedup vs baseline: 1.0146x; 1.0146x over previous
//
#include <hip/hip_runtime.h>
#include <hip/hip_bf16.h>

// SkeletalConv via MFMA + LDS staging (fragment-contiguous layout) +
// LDS-transpose aligned-store epilogue. Round-13 structure (best, 40.7us)
// with NT stores reverted (round 14: -2%) and C-tile stride tightened
// CWT 292->272 -> LDS 18944->17664B -> 9 blocks/CU (was 8).
// x: (16, 25, 65536) f32, W: (48, 16, 16, 3) f32, b: (48, 16) f32
// out: (16, 24, 65534) f32
// out[co,e,t] = 0.5*sum_{j,ci,k} W[2e+j,co,ci,k]*x[ci,e+j,t+k] + 0.5*(b[2e,co]+b[2e+1,co])
//
// Staging layout lds[q][col][d], q=ci>>2, d=ci&3: one ds_read_b128 per
// (tile,tap) B-fragment. A = W-frag per lane from 6 aligned float4 loads.
// C row=co, col=t. Epilogue: C -> LDS [co][col] tile shifted per-row so
// bulk stores are 64B-line-aligned full-line float4 (WRITE_SIZE == output
// exactly; round 12 evidence). Per-row valid window [16-srw, 272) fits
// stride 272; reads may poke +-48 into neighbor rows -> garbage lanes are
// predicated off at the store; +64 front pad covers row 0.

#define NJ    25
#define LSEQ  65536
#define NE    24
#define LOUTN (LSEQ - 2)               // 65534 valid t
#define CQ    258                      // staging cols per quad (256 + 2 halo)
#define CWT   272                      // C-tile row stride (dwords), mult of 4
#define LDSN  (64 + 16 * CWT)          // 4416 dwords = 17664 B (>= staging 4128)

typedef __attribute__((ext_vector_type(8))) short bf16x8;
typedef __attribute__((ext_vector_type(4))) float f32x4;

static __device__ __forceinline__ unsigned cvtpk(float lo, float hi) {
    union { __hip_bfloat162 h; unsigned u; } cv;
    cv.h = __float22bfloat162_rn(make_float2(lo, hi));   // v_cvt_pk_bf16_f32
    return cv.u;
}

__global__ __launch_bounds__(256)
void skel_mfma_kernel(const float* __restrict__ x,
                      const float* __restrict__ W,
                      const float* __restrict__ b,
                      float* __restrict__ out)
{
    __shared__ unsigned lds[LDSN];      // staging tile, later aliased as C tile

    const int e   = blockIdx.y;
    const int tb  = blockIdx.x * 256;
    const int tid = threadIdx.x;
    const int l   = tid & 63, wv = tid >> 6;
    const int g   = l >> 4,  lc = l & 15;

    // ---- A fragments (W): lane l -> co=lc, slots kk=8g+i, 3 taps ----
    const float* wp = W + ((size_t)((2 * e) * 16 + lc) * 16 + 4 * g) * 3;
    f32x4 wj0[3], wj1[3];
    #pragma unroll
    for (int q = 0; q < 3; ++q) {
        wj0[q] = *reinterpret_cast<const f32x4*>(wp + 4 * q);
        wj1[q] = *reinterpret_cast<const f32x4*>(wp + 768 + 4 * q);
    }
    union { unsigned u[4]; bf16x8 v8; } Aw[3];
    #pragma unroll
    for (int d = 0; d < 4; ++d)
        #pragma unroll
        for (int k = 0; k < 3; ++k) {
            const int f = d * 3 + k;            // compile-time after unroll
            Aw[k].u[d] = cvtpk(wj0[f >> 2][f & 3], wj1[f >> 2][f & 3]);
        }

    // ---- folded bias for rows co = 4g+r ----
    const f32x4 b0 = *reinterpret_cast<const f32x4*>(b + (size_t)(2 * e) * 16 + 4 * g);
    const f32x4 b1 = *reinterpret_cast<const f32x4*>(b + (size_t)(2 * e + 1) * 16 + 4 * g);
    f32x4 bias;
    #pragma unroll
    for (int r = 0; r < 4; ++r) bias[r] = 0.5f * (b0[r] + b1[r]);

    // ---- stage: thread = (quad qs, col cs); 32 coalesced dword loads ----
    {
        const int qs = tid >> 6;                // quad (= wave)
        const int cs = tid & 63;
        const float* xr0 = x + (size_t)((4 * qs + 0) * NJ + e) * LSEQ + tb;
        const float* xr1 = x + (size_t)((4 * qs + 1) * NJ + e) * LSEQ + tb;
        const float* xr2 = x + (size_t)((4 * qs + 2) * NJ + e) * LSEQ + tb;
        const float* xr3 = x + (size_t)((4 * qs + 3) * NJ + e) * LSEQ + tb;
        #pragma unroll
        for (int s = 0; s < 4; ++s) {
            const int col = 64 * s + cs;        // never OOB (tb+255 <= 65535)
            uint4 pk;
            pk.x = cvtpk(xr0[col], xr0[col + LSEQ]);
            pk.y = cvtpk(xr1[col], xr1[col + LSEQ]);
            pk.z = cvtpk(xr2[col], xr2[col + LSEQ]);
            pk.w = cvtpk(xr3[col], xr3[col + LSEQ]);
            *reinterpret_cast<uint4*>(&lds[(qs * CQ + col) * 4]) = pk;
        }
    }
    if (tid < 32) {                             // halo cols 256,257 (all 16 ci)
        const int ci = tid >> 1, h = tid & 1;
        const int gc = min(tb + 256 + h, LSEQ - 1); // clamp (last chunk only)
        const float* xl = x + (size_t)(ci * NJ + e) * LSEQ;
        lds[((ci >> 2) * CQ + 256 + h) * 4 + (ci & 3)] = cvtpk(xl[gc], xl[gc + LSEQ]);
    }
    __syncthreads();

    // ---- compute: wave wv owns cols wv*64..wv*64+63; keep C in regs ----
    f32x4 C[4];
    #pragma unroll
    for (int tc = 0; tc < 4; ++tc) {
        const int cb = wv * 64 + tc * 16 + lc;      // col within chunk
        f32x4 acc = {0.f, 0.f, 0.f, 0.f};
        #pragma unroll
        for (int k = 0; k < 3; ++k) {
            union { uint4 q4; bf16x8 v8; } Bx;     // one b128 = whole fragment
            Bx.q4 = *reinterpret_cast<const uint4*>(&lds[(g * CQ + cb + k) * 4]);
            acc = __builtin_amdgcn_mfma_f32_16x16x32_bf16(Aw[k].v8, Bx.v8, acc, 0, 0, 0);
        }
        C[tc] = acc;
    }
    __syncthreads();                                // staging reads complete

    // ---- epilogue 1: final values -> LDS C-tile [co][col] ----
    {
        float* cl = reinterpret_cast<float*>(lds);
        int srw[4];
        #pragma unroll
        for (int r = 0; r < 4; ++r) {
            const int row = 4 * g + r;              // co
            const size_t rb = (size_t)(row * NE + e) * LOUTN + tb;
            srw[r] = (int)((16 - (rb & 15)) & 15);  // row alignment phase
        }
        #pragma unroll
        for (int tc = 0; tc < 4; ++tc) {
            const int cb = wv * 64 + tc * 16 + lc;
            #pragma unroll
            for (int r = 0; r < 4; ++r)
                cl[64 + (4 * g + r) * CWT + 16 + cb - srw[r]] = fmaf(0.5f, C[tc][r], bias[r]);
        }
    }
    __syncthreads();                                // C-tile complete

    // ---- epilogue 2: per-row 64B-line-aligned float4 stores ----
    {
        const float* cl = reinterpret_cast<const float*>(lds);
        const int row = tid >> 4;                   // co
        const int q   = tid & 15;
        const size_t rbase = (size_t)(row * NE + e) * LOUTN;
        const int srow = (int)((16 - ((rbase + tb) & 15)) & 15);
        #pragma unroll
        for (int s = 0; s < 5; ++s) {
            const int col = srow - 64 + 64 * s + 4 * q;   // block-frame col
            const f32x4 v = *reinterpret_cast<const f32x4*>(
                cl + 64 + row * CWT - 48 + 64 * s + 4 * q);
            const long t = (long)tb + col;
            if (col >= 0 && col + 3 < 256 && t + 3 < LOUTN) {
                *reinterpret_cast<f32x4*>(out + rbase + t) = v;   // full line
            } else {
                #pragma unroll
                for (int d = 0; d < 4; ++d)
                    if (col + d >= 0 && col + d < 256 && t + d < LOUTN)
                        out[rbase + t + d] = v[d];
            }
        }
    }
}

extern "C" void kernel_launch(void* const* d_in, const int* in_sizes, int n_in,
                              void* d_out, int out_size, void* d_ws, size_t ws_size,
                              hipStream_t stream)
{
    const float* x = (const float*)d_in[0];
    const float* W = (const float*)d_in[1];
    const float* b = (const float*)d_in[2];
    float* out     = (float*)d_out;

    dim3 grid((LOUTN + 255) / 256, NE);      // 256 x 24 blocks, single launch
    skel_mfma_kernel<<<grid, 256, 0, stream>>>(x, W, b, out);
}

// Round 17
// 40.230 us; speedup vs baseline: 1.0348x; 1.0199x over previous
//
#include <hip/hip_runtime.h>
#include <hip/hip_bf16.h>

// SkeletalConv via MFMA + LDS staging (fragment-contiguous layout) +
// LDS-transpose aligned-store epilogue. EXACT round-13 kernel (best: 40.73us,
// passed). Subsequent probes all null/negative and are reverted:
//   r11 cross-chunk prefetch (null), r14 NT stores (-2%), r15 CWT=272
//   occupancy bump (null), r16 batched staging loads (no gain + replay
//   nondeterminism -> rejected).
// x: (16, 25, 65536) f32, W: (48, 16, 16, 3) f32, b: (48, 16) f32
// out: (16, 24, 65534) f32
// out[co,e,t] = 0.5*sum_{j,ci,k} W[2e+j,co,ci,k]*x[ci,e+j,t+k] + 0.5*(b[2e,co]+b[2e+1,co])
//
// Staging layout lds[q][col][d], q=ci>>2, d=ci&3: one ds_read_b128 per
// (tile,tap) B-fragment. A = W-frag per lane from 6 aligned float4 loads.
// C row=co, col=t. Epilogue: C -> LDS [co][col] tile shifted per-row so
// bulk stores are 64B-line-aligned full-line float4 (WRITE_SIZE == output
// exactly; round-12 evidence).

#define NJ    25
#define LSEQ  65536
#define NE    24
#define LOUTN (LSEQ - 2)               // 65534 valid t
#define CQ    258                      // staging cols per quad (256 + 2 halo)
#define CWT   292                      // C-tile row stride (dwords), mult of 4
#define LDSN  (64 + 16 * CWT)          // 4736 dwords = 18944 B (>= staging 4128)

typedef __attribute__((ext_vector_type(8))) short bf16x8;
typedef __attribute__((ext_vector_type(4))) float f32x4;

static __device__ __forceinline__ unsigned cvtpk(float lo, float hi) {
    union { __hip_bfloat162 h; unsigned u; } cv;
    cv.h = __float22bfloat162_rn(make_float2(lo, hi));   // v_cvt_pk_bf16_f32
    return cv.u;
}

__global__ __launch_bounds__(256)
void skel_mfma_kernel(const float* __restrict__ x,
                      const float* __restrict__ W,
                      const float* __restrict__ b,
                      float* __restrict__ out)
{
    __shared__ unsigned lds[LDSN];      // staging tile, later aliased as C tile

    const int e   = blockIdx.y;
    const int tb  = blockIdx.x * 256;
    const int tid = threadIdx.x;
    const int l   = tid & 63, wv = tid >> 6;
    const int g   = l >> 4,  lc = l & 15;

    // ---- A fragments (W): lane l -> co=lc, slots kk=8g+i, 3 taps ----
    const float* wp = W + ((size_t)((2 * e) * 16 + lc) * 16 + 4 * g) * 3;
    f32x4 wj0[3], wj1[3];
    #pragma unroll
    for (int q = 0; q < 3; ++q) {
        wj0[q] = *reinterpret_cast<const f32x4*>(wp + 4 * q);
        wj1[q] = *reinterpret_cast<const f32x4*>(wp + 768 + 4 * q);
    }
    union { unsigned u[4]; bf16x8 v8; } Aw[3];
    #pragma unroll
    for (int d = 0; d < 4; ++d)
        #pragma unroll
        for (int k = 0; k < 3; ++k) {
            const int f = d * 3 + k;            // compile-time after unroll
            Aw[k].u[d] = cvtpk(wj0[f >> 2][f & 3], wj1[f >> 2][f & 3]);
        }

    // ---- folded bias for rows co = 4g+r ----
    const f32x4 b0 = *reinterpret_cast<const f32x4*>(b + (size_t)(2 * e) * 16 + 4 * g);
    const f32x4 b1 = *reinterpret_cast<const f32x4*>(b + (size_t)(2 * e + 1) * 16 + 4 * g);
    f32x4 bias;
    #pragma unroll
    for (int r = 0; r < 4; ++r) bias[r] = 0.5f * (b0[r] + b1[r]);

    // ---- stage: thread = (quad qs, col cs); 32 coalesced dword loads ----
    {
        const int qs = tid >> 6;                // quad (= wave)
        const int cs = tid & 63;
        const float* xr0 = x + (size_t)((4 * qs + 0) * NJ + e) * LSEQ + tb;
        const float* xr1 = x + (size_t)((4 * qs + 1) * NJ + e) * LSEQ + tb;
        const float* xr2 = x + (size_t)((4 * qs + 2) * NJ + e) * LSEQ + tb;
        const float* xr3 = x + (size_t)((4 * qs + 3) * NJ + e) * LSEQ + tb;
        #pragma unroll
        for (int s = 0; s < 4; ++s) {
            const int col = 64 * s + cs;        // never OOB (tb+255 <= 65535)
            uint4 pk;
            pk.x = cvtpk(xr0[col], xr0[col + LSEQ]);
            pk.y = cvtpk(xr1[col], xr1[col + LSEQ]);
            pk.z = cvtpk(xr2[col], xr2[col + LSEQ]);
            pk.w = cvtpk(xr3[col], xr3[col + LSEQ]);
            *reinterpret_cast<uint4*>(&lds[(qs * CQ + col) * 4]) = pk;
        }
    }
    if (tid < 32) {                             // halo cols 256,257 (all 16 ci)
        const int ci = tid >> 1, h = tid & 1;
        const int gc = min(tb + 256 + h, LSEQ - 1); // clamp (last chunk only)
        const float* xl = x + (size_t)(ci * NJ + e) * LSEQ;
        lds[((ci >> 2) * CQ + 256 + h) * 4 + (ci & 3)] = cvtpk(xl[gc], xl[gc + LSEQ]);
    }
    __syncthreads();

    // ---- compute: wave wv owns cols wv*64..wv*64+63; keep C in regs ----
    f32x4 C[4];
    #pragma unroll
    for (int tc = 0; tc < 4; ++tc) {
        const int cb = wv * 64 + tc * 16 + lc;      // col within chunk
        f32x4 acc = {0.f, 0.f, 0.f, 0.f};
        #pragma unroll
        for (int k = 0; k < 3; ++k) {
            union { uint4 q4; bf16x8 v8; } Bx;     // one b128 = whole fragment
            Bx.q4 = *reinterpret_cast<const uint4*>(&lds[(g * CQ + cb + k) * 4]);
            acc = __builtin_amdgcn_mfma_f32_16x16x32_bf16(Aw[k].v8, Bx.v8, acc, 0, 0, 0);
        }
        C[tc] = acc;
    }
    __syncthreads();                                // staging reads complete

    // ---- epilogue 1: final values -> LDS C-tile [co][col] ----
    {
        float* cl = reinterpret_cast<float*>(lds);
        int srw[4];
        #pragma unroll
        for (int r = 0; r < 4; ++r) {
            const int row = 4 * g + r;              // co
            const size_t rb = (size_t)(row * NE + e) * LOUTN + tb;
            srw[r] = (int)((16 - (rb & 15)) & 15);  // row alignment phase
        }
        #pragma unroll
        for (int tc = 0; tc < 4; ++tc) {
            const int cb = wv * 64 + tc * 16 + lc;
            #pragma unroll
            for (int r = 0; r < 4; ++r)
                cl[64 + (4 * g + r) * CWT + 16 + cb - srw[r]] = fmaf(0.5f, C[tc][r], bias[r]);
        }
    }
    __syncthreads();                                // C-tile complete

    // ---- epilogue 2: per-row 64B-aligned float4 stores ----
    {
        const float* cl = reinterpret_cast<const float*>(lds);
        const int row = tid >> 4;                   // co
        const int q   = tid & 15;
        const size_t rbase = (size_t)(row * NE + e) * LOUTN;
        const int srow = (int)((16 - ((rbase + tb) & 15)) & 15);
        #pragma unroll
        for (int s = 0; s < 5; ++s) {
            const int col = srow - 64 + 64 * s + 4 * q;   // block-frame col
            const f32x4 v = *reinterpret_cast<const f32x4*>(
                cl + 64 + row * CWT - 48 + 64 * s + 4 * q);
            const long t = (long)tb + col;
            if (col >= 0 && col + 3 < 256 && t + 3 < LOUTN) {
                *reinterpret_cast<f32x4*>(out + rbase + t) = v;   // full line
            } else {
                #pragma unroll
                for (int d = 0; d < 4; ++d)
                    if (col + d >= 0 && col + d < 256 && t + d < LOUTN)
                        out[rbase + t + d] = v[d];
            }
        }
    }
}

extern "C" void kernel_launch(void* const* d_in, const int* in_sizes, int n_in,
                              void* d_out, int out_size, void* d_ws, size_t ws_size,
                              hipStream_t stream)
{
    const float* x = (const float*)d_in[0];
    const float* W = (const float*)d_in[1];
    const float* b = (const float*)d_in[2];
    float* out     = (float*)d_out;

    dim3 grid((LOUTN + 255) / 256, NE);      // 256 x 24 blocks, single launch
    skel_mfma_kernel<<<grid, 256, 0, stream>>>(x, W, b, out);
}